// Round 1
// baseline (1965.160 us; speedup 1.0000x reference)
//
#include <hip/hip_runtime.h>
#include <hip/hip_bf16.h>
#include <math.h>

// ---- problem constants ----
constexpr int Ll = 2048, Bb = 4, DIi = 256, Hh = 4;
constexpr int TOK = Bb * Ll;       // 8192 tokens
constexpr int NC = 64;             // scan chunks per sequence
constexpr int CH = 32;             // chunk length (NC*CH = L)

#define DEV __device__ __forceinline__

DEV float siluf(float v)     { return v / (1.f + expf(-v)); }
DEV float softplusf(float v) { return (v > 20.f) ? v : log1pf(expf(v)); }
DEV float geluf(float v)     { return 0.5f * v * (1.f + erff(v * 0.7071067811865476f)); }

// ---------------- embedding ----------------
// x[tok,d] = emb[id,d] + type_emb[tt,d] + (enc @ te_w.T)[d] + te_b[d]
__global__ __launch_bounds__(128) void embed_kernel(
    const int* __restrict__ ids, const int* __restrict__ tts,
    const float* __restrict__ ts, const float* __restrict__ emb,
    const float* __restrict__ temb, const float* __restrict__ freqs,
    const float* __restrict__ phases, const float* __restrict__ tew,
    const float* __restrict__ teb, float* __restrict__ x)
{
    int tok = blockIdx.x;
    int d = threadIdx.x;
    __shared__ float enc[128];
    float tval = ts[tok];
    int j = d & 63;
    float a = tval * freqs[j] + phases[j];
    enc[d] = (d < 64) ? sinf(a) : cosf(a);
    __syncthreads();
    float acc = teb[d];
    const float* wrow = tew + (size_t)d * 128;
#pragma unroll 8
    for (int k = 0; k < 128; k++) acc += enc[k] * wrow[k];
    int id = ids[tok];
    int tt = tts[tok];
    x[(size_t)tok * 128 + d] = emb[(size_t)id * 128 + d] + temb[(size_t)tt * 128 + d] + acc;
}

// ---------------- layernorm (D=128), one wave per token ----------------
__global__ __launch_bounds__(256) void ln_kernel(
    const float* __restrict__ x, const float* __restrict__ w,
    const float* __restrict__ b, float* __restrict__ out)
{
    int wid = threadIdx.x >> 6, lane = threadIdx.x & 63;
    int tok = blockIdx.x * 4 + wid;
    const float* xr = x + (size_t)tok * 128;
    float2 v = *(const float2*)(xr + lane * 2);
    float s = v.x + v.y, sq = v.x * v.x + v.y * v.y;
#pragma unroll
    for (int o = 32; o > 0; o >>= 1) { s += __shfl_xor(s, o); sq += __shfl_xor(sq, o); }
    float mu = s * (1.f / 128.f);
    float var = sq * (1.f / 128.f) - mu * mu;
    float rstd = rsqrtf(var + 1e-5f);
    int d0 = lane * 2;
    out[(size_t)tok * 128 + d0]     = (v.x - mu) * rstd * w[d0]     + b[d0];
    out[(size_t)tok * 128 + d0 + 1] = (v.y - mu) * rstd * w[d0 + 1] + b[d0 + 1];
}

// ---------------- generic fp32 GEMM: C[M,N] = act(A[M,K] @ W[N,K].T + bias) ----------------
// BM=64, BN=64, BK=16, 256 threads, 4x4 per thread. ADD: C += result (residual).
template <int ACT, bool BIAS, bool ADD>
__global__ __launch_bounds__(256) void gemm_kernel(
    const float* __restrict__ A, const float* __restrict__ W,
    const float* __restrict__ bias, float* __restrict__ C,
    int M, int N, int Kd, int lda, int ldc)
{
    __shared__ float As[16][68];
    __shared__ float Ws[16][68];
    int bm0 = blockIdx.x * 64, bn0 = blockIdx.y * 64;
    int tid = threadIdx.x;
    int ty = tid >> 4, tx = tid & 15;
    float acc[4][4] = {};
    int lr = tid >> 2;            // 0..63 (tile row for staging)
    int kc = (tid & 3) << 2;      // 0,4,8,12
    for (int k0 = 0; k0 < Kd; k0 += 16) {
        float4 av = *(const float4*)(A + (size_t)(bm0 + lr) * lda + k0 + kc);
        float4 wv = *(const float4*)(W + (size_t)(bn0 + lr) * Kd + k0 + kc);
        As[kc][lr] = av.x; As[kc + 1][lr] = av.y; As[kc + 2][lr] = av.z; As[kc + 3][lr] = av.w;
        Ws[kc][lr] = wv.x; Ws[kc + 1][lr] = wv.y; Ws[kc + 2][lr] = wv.z; Ws[kc + 3][lr] = wv.w;
        __syncthreads();
#pragma unroll
        for (int k = 0; k < 16; k++) {
            float a[4], w[4];
            *(float4*)a = *(const float4*)&As[k][ty << 2];
            *(float4*)w = *(const float4*)&Ws[k][tx << 2];
#pragma unroll
            for (int i = 0; i < 4; i++)
#pragma unroll
                for (int j = 0; j < 4; j++) acc[i][j] += a[i] * w[j];
        }
        __syncthreads();
    }
#pragma unroll
    for (int i = 0; i < 4; i++) {
        int row = bm0 + (ty << 2) + i;
        int col = bn0 + (tx << 2);
        float v[4];
#pragma unroll
        for (int j = 0; j < 4; j++) {
            float t = acc[i][j];
            if (BIAS) t += bias[col + j];
            if (ACT == 1) t = softplusf(t);
            if (ACT == 2) t = geluf(t);
            v[j] = t;
        }
        float* p = C + (size_t)row * ldc + col;
        if (ADD) {
            float4 old = *(const float4*)p;
            v[0] += old.x; v[1] += old.y; v[2] += old.z; v[3] += old.w;
        }
        *(float4*)p = make_float4(v[0], v[1], v[2], v[3]);
    }
}

// ---------------- causal depthwise conv (K=4) + silu ----------------
// xc[b,t,c] = silu( sum_k xp[b,t-3+k,c] * cw[c,k] + cb[c] ), xp = xz[...,:256]
__global__ __launch_bounds__(256) void conv_kernel(
    const float* __restrict__ xz, const float* __restrict__ cw,
    const float* __restrict__ cb, float* __restrict__ xc)
{
    int g = blockIdx.x * 256 + threadIdx.x;   // B*L*DI threads
    int c = g & 255;
    int t = (g >> 8) & 2047;
    int b = g >> 19;
    float4 w4 = *(const float4*)(cw + (size_t)c * 4);
    float acc = cb[c];
    const float* base = xz + ((size_t)b * 2048 + t) * 512 + c;
    if (t >= 3) {
        acc += base[-3 * 512] * w4.x + base[-2 * 512] * w4.y + base[-512] * w4.z + base[0] * w4.w;
    } else {
        const float wv[4] = {w4.x, w4.y, w4.z, w4.w};
#pragma unroll
        for (int kk = 0; kk < 4; kk++) {
            int tt = t - 3 + kk;
            if (tt >= 0) acc += xz[((size_t)b * 2048 + tt) * 512 + c] * wv[kk];
        }
    }
    xc[g] = siluf(acc);
}

// ---------------- B/C projections (N=16 each) ----------------
__global__ __launch_bounds__(256) void bc_kernel(
    const float* __restrict__ xc, const float* __restrict__ Bw,
    const float* __restrict__ Cw, float* __restrict__ bm, float* __restrict__ cm)
{
    __shared__ float xs[16][260];
    int t0 = blockIdx.x * 16;
    for (int idx = threadIdx.x; idx < 16 * 64; idx += 256) {
        int r = idx >> 6, c4 = (idx & 63) << 2;
        *(float4*)&xs[r][c4] = *(const float4*)(xc + (size_t)(t0 + r) * 256 + c4);
    }
    __syncthreads();
    int tk = threadIdx.x >> 4, j = threadIdx.x & 15;
    float accB = 0.f, accC = 0.f;
#pragma unroll 4
    for (int k = 0; k < 256; k += 4) {
        float xv[4], bw[4], cw[4];
        *(float4*)xv = *(const float4*)&xs[tk][k];
        *(float4*)bw = *(const float4*)(Bw + (size_t)j * 256 + k);
        *(float4*)cw = *(const float4*)(Cw + (size_t)j * 256 + k);
#pragma unroll
        for (int q = 0; q < 4; q++) { accB += xv[q] * bw[q]; accC += xv[q] * cw[q]; }
    }
    bm[(size_t)(t0 + tk) * 16 + j] = accB;
    cm[(size_t)(t0 + tk) * 16 + j] = accC;
}

// ---------------- scan phase 1: per-chunk local final state F + sum(dt) ----------------
__global__ __launch_bounds__(256) void scan1_kernel(
    const float* __restrict__ dt, const float* __restrict__ xc,
    const float* __restrict__ bm, const float* __restrict__ Alog,
    float* __restrict__ F, float* __restrict__ sumdt)
{
    int c = threadIdx.x;
    int k = blockIdx.x & (NC - 1);
    int b = blockIdx.x >> 6;
    __shared__ float sB[CH][16];
    int t0 = k * CH;
    if (threadIdx.x < CH * 4) {
        int r = threadIdx.x >> 2, c4 = (threadIdx.x & 3) << 2;
        *(float4*)&sB[r][c4] = *(const float4*)(bm + ((size_t)b * 2048 + t0 + r) * 16 + c4);
    }
    float A[16];
#pragma unroll
    for (int s = 0; s < 16; s++) A[s] = -expf(Alog[(size_t)c * 16 + s]);
    __syncthreads();
    float h[16] = {};
    float sd = 0.f;
    size_t base = ((size_t)b * 2048 + t0) * 256 + c;
    for (int tt = 0; tt < CH; tt++) {
        float d  = dt[base + (size_t)tt * 256];
        float xv = xc[base + (size_t)tt * 256];
        sd += d;
        float xdt = xv * d;
#pragma unroll
        for (int s = 0; s < 16; s++) h[s] = h[s] * expf(A[s] * d) + xdt * sB[tt][s];
    }
    size_t fo = (((size_t)b * NC + k) * 256 + c) * 16;
#pragma unroll
    for (int s = 0; s < 16; s += 4) *(float4*)(F + fo + s) = make_float4(h[s], h[s+1], h[s+2], h[s+3]);
    sumdt[((size_t)b * NC + k) * 256 + c] = sd;
}

// ---------------- scan phase 2: sequential prefix over chunks ----------------
__global__ __launch_bounds__(256) void scan2_kernel(
    const float* __restrict__ F, const float* __restrict__ sumdt,
    const float* __restrict__ Alog, float* __restrict__ Hs)
{
    int g = blockIdx.x * 256 + threadIdx.x;  // B*DI*DS = 16384
    int s = g & 15, c = (g >> 4) & 255, b = g >> 12;
    float A = -expf(Alog[(size_t)c * 16 + s]);
    float h = 0.f;
    for (int k = 0; k < NC; k++) {
        size_t o = (((size_t)b * NC + k) * 256 + c) * 16 + s;
        Hs[o] = h;
        h = h * expf(A * sumdt[((size_t)b * NC + k) * 256 + c]) + F[o];
    }
}

// ---------------- scan phase 3: replay with true h0, emit gated y ----------------
__global__ __launch_bounds__(256) void scan3_kernel(
    const float* __restrict__ dt, const float* __restrict__ xc,
    const float* __restrict__ bm, const float* __restrict__ cm,
    const float* __restrict__ xz, const float* __restrict__ Alog,
    const float* __restrict__ Dp, const float* __restrict__ Hs,
    float* __restrict__ y)
{
    int c = threadIdx.x;
    int k = blockIdx.x & (NC - 1);
    int b = blockIdx.x >> 6;
    __shared__ float sB[CH][16], sC[CH][16];
    int t0 = k * CH;
    if (threadIdx.x < CH * 4) {
        int r = threadIdx.x >> 2, c4 = (threadIdx.x & 3) << 2;
        *(float4*)&sB[r][c4] = *(const float4*)(bm + ((size_t)b * 2048 + t0 + r) * 16 + c4);
        *(float4*)&sC[r][c4] = *(const float4*)(cm + ((size_t)b * 2048 + t0 + r) * 16 + c4);
    }
    float A[16];
#pragma unroll
    for (int s = 0; s < 16; s++) A[s] = -expf(Alog[(size_t)c * 16 + s]);
    __syncthreads();
    float h[16];
    size_t ho = (((size_t)b * NC + k) * 256 + c) * 16;
#pragma unroll
    for (int s = 0; s < 16; s++) h[s] = Hs[ho + s];
    float Dv = Dp[c];
    size_t base  = ((size_t)b * 2048 + t0) * 256 + c;
    size_t zbase = ((size_t)b * 2048 + t0) * 512 + 256 + c;
    for (int tt = 0; tt < CH; tt++) {
        float d  = dt[base + (size_t)tt * 256];
        float xv = xc[base + (size_t)tt * 256];
        float xdt = xv * d;
        float yv = 0.f;
#pragma unroll
        for (int s = 0; s < 16; s++) {
            h[s] = h[s] * expf(A[s] * d) + xdt * sB[tt][s];
            yv += h[s] * sC[tt][s];
        }
        yv += xv * Dv;
        float zv = xz[zbase + (size_t)tt * 512];
        y[base + (size_t)tt * 256] = yv * siluf(zv);
    }
}

// ---------------- flash attention fp32: block per (b,h,64-query tile) ----------------
__global__ __launch_bounds__(256) void attn_kernel(
    const float* __restrict__ qkv, float* __restrict__ o_out)
{
    int qt = blockIdx.x, h = blockIdx.y, b = blockIdx.z;
    __shared__ float Qs[32][68];
    __shared__ float Ks[32][68];
    __shared__ float Vs[64][36];
    __shared__ float Ps[64][68];
    __shared__ float sResc[64], sL[64];
    int tid = threadIdx.x;
    const float scale = 0.17677669529663687f;   // 1/sqrt(32)
    size_t qbase = ((size_t)b * 2048 + qt * 64) * 384 + (size_t)h * 32;
    for (int idx = tid; idx < 64 * 8; idx += 256) {
        int r = idx >> 3, d4 = (idx & 7) << 2;
        float4 v = *(const float4*)(qkv + qbase + (size_t)r * 384 + d4);
        Qs[d4][r] = v.x * scale; Qs[d4 + 1][r] = v.y * scale;
        Qs[d4 + 2][r] = v.z * scale; Qs[d4 + 3][r] = v.w * scale;
    }
    int qg = tid >> 4, kg = tid & 15;       // S-phase mapping (4 q rows x 4 k cols)
    int qr = tid >> 2, dg = (tid & 3) << 3; // PV mapping (1 q row x 8 d)
    float m[4], l[4];
#pragma unroll
    for (int i = 0; i < 4; i++) { m[i] = -1e30f; l[i] = 0.f; }
    float oacc[8] = {};
    for (int kt = 0; kt < 32; kt++) {
        size_t kbase = ((size_t)b * 2048 + kt * 64) * 384 + 128 + (size_t)h * 32;
        size_t vbase = kbase + 128;
        __syncthreads();   // previous PV / Q stage done before overwrite
        for (int idx = tid; idx < 64 * 8; idx += 256) {
            int r = idx >> 3, d4 = (idx & 7) << 2;
            float4 kv = *(const float4*)(qkv + kbase + (size_t)r * 384 + d4);
            Ks[d4][r] = kv.x; Ks[d4 + 1][r] = kv.y; Ks[d4 + 2][r] = kv.z; Ks[d4 + 3][r] = kv.w;
            float4 vv = *(const float4*)(qkv + vbase + (size_t)r * 384 + d4);
            *(float4*)&Vs[r][d4] = vv;
        }
        __syncthreads();
        // S = Q K^T (scaled), 4x4 per thread
        float s[4][4] = {};
#pragma unroll
        for (int d = 0; d < 32; d++) {
            float a[4], w[4];
            *(float4*)a = *(const float4*)&Qs[d][qg << 2];
            *(float4*)w = *(const float4*)&Ks[d][kg << 2];
#pragma unroll
            for (int i = 0; i < 4; i++)
#pragma unroll
                for (int j = 0; j < 4; j++) s[i][j] += a[i] * w[j];
        }
        // online softmax over 16 kg lanes (64 keys)
#pragma unroll
        for (int i = 0; i < 4; i++) {
            float rm = fmaxf(fmaxf(s[i][0], s[i][1]), fmaxf(s[i][2], s[i][3]));
            rm = fmaxf(rm, __shfl_xor(rm, 1)); rm = fmaxf(rm, __shfl_xor(rm, 2));
            rm = fmaxf(rm, __shfl_xor(rm, 4)); rm = fmaxf(rm, __shfl_xor(rm, 8));
            float mn = fmaxf(m[i], rm);
            float rs = expf(m[i] - mn);
            float ps = 0.f;
#pragma unroll
            for (int j = 0; j < 4; j++) {
                float p = expf(s[i][j] - mn);
                Ps[(qg << 2) + i][(kg << 2) + j] = p;
                ps += p;
            }
            ps += __shfl_xor(ps, 1); ps += __shfl_xor(ps, 2);
            ps += __shfl_xor(ps, 4); ps += __shfl_xor(ps, 8);
            l[i] = l[i] * rs + ps;
            m[i] = mn;
            if (kg == 0) sResc[(qg << 2) + i] = rs;
        }
        __syncthreads();
        // PV
        float rs = sResc[qr];
#pragma unroll
        for (int d = 0; d < 8; d++) oacc[d] *= rs;
#pragma unroll 8
        for (int k2 = 0; k2 < 64; k2++) {
            float p = Ps[qr][k2];
            float v[8];
            *(float4*)v       = *(const float4*)&Vs[k2][dg];
            *(float4*)(v + 4) = *(const float4*)&Vs[k2][dg + 4];
#pragma unroll
            for (int d = 0; d < 8; d++) oacc[d] += p * v[d];
        }
    }
    if (kg == 0) {
#pragma unroll
        for (int i = 0; i < 4; i++) sL[(qg << 2) + i] = l[i];
    }
    __syncthreads();
    float inv = 1.f / sL[qr];
    size_t obase = ((size_t)b * 2048 + qt * 64 + qr) * 128 + (size_t)h * 32 + dg;
    *(float4*)(o_out + obase)     = make_float4(oacc[0]*inv, oacc[1]*inv, oacc[2]*inv, oacc[3]*inv);
    *(float4*)(o_out + obase + 4) = make_float4(oacc[4]*inv, oacc[5]*inv, oacc[6]*inv, oacc[7]*inv);
}

// ---------------- head: LN(cls) @ h_w.T + h_b ----------------
__global__ __launch_bounds__(128) void head_kernel(
    const float* __restrict__ x, const float* __restrict__ w,
    const float* __restrict__ bsp, const float* __restrict__ hw,
    const float* __restrict__ hb, float* __restrict__ out)
{
    int bb = blockIdx.x;
    int d = threadIdx.x;
    int wid = d >> 6, lane = d & 63;
    float v = x[(size_t)bb * 2048 * 128 + d];
    float s = v, sq = v * v;
#pragma unroll
    for (int o = 32; o > 0; o >>= 1) { s += __shfl_xor(s, o); sq += __shfl_xor(sq, o); }
    __shared__ float red[4];
    if (lane == 0) { red[wid] = s; red[2 + wid] = sq; }
    __syncthreads();
    s = red[0] + red[1]; sq = red[2] + red[3];
    float mu = s * (1.f / 128.f);
    float var = sq * (1.f / 128.f) - mu * mu;
    float xn = (v - mu) * rsqrtf(var + 1e-5f) * w[d] + bsp[d];
    float pr = xn * hw[d];
#pragma unroll
    for (int o = 32; o > 0; o >>= 1) pr += __shfl_xor(pr, o);
    __syncthreads();
    if (lane == 0) red[wid] = pr;
    __syncthreads();
    if (d == 0) out[bb] = red[0] + red[1] + hb[0];
}

// ---------------- workspace layout (floats) ----------------
constexpr size_t OFF_X  = 0;                         // 1M
constexpr size_t OFF_XN = (size_t)1 << 20;           // 1M
constexpr size_t OFF_XZ = (size_t)2 << 20;           // 4M  (xz in mamba, ff in attn)
constexpr size_t OFF_XC = (size_t)6 << 20;           // 2M  (xc; qkv spans XC..XC+3M)
constexpr size_t OFF_DT = (size_t)8 << 20;           // 2M
constexpr size_t OFF_Y  = (size_t)10 << 20;          // 2M  (y in mamba, attn_out in attn)
constexpr size_t OFF_BM = (size_t)12 << 20;          // 131072
constexpr size_t OFF_CM = OFF_BM + 131072;           // 131072
constexpr size_t OFF_SD = OFF_CM + 131072;           // 65536
constexpr size_t OFF_F  = OFF_SD + 65536;            // 1M
constexpr size_t OFF_HS = OFF_F + ((size_t)1 << 20); // 1M
constexpr size_t WS_FLOATS = OFF_HS + ((size_t)1 << 20);

extern "C" void kernel_launch(void* const* d_in, const int* in_sizes, int n_in,
                              void* d_out, int out_size, void* d_ws, size_t ws_size,
                              hipStream_t stream)
{
    const int*   ids   = (const int*)d_in[0];
    const int*   tts   = (const int*)d_in[1];
    const float* tstmp = (const float*)d_in[2];
    const float* emb   = (const float*)d_in[3];
    const float* temb  = (const float*)d_in[4];
    const float* tef   = (const float*)d_in[5];
    const float* tep   = (const float*)d_in[6];
    const float* tew   = (const float*)d_in[7];
    const float* tebi  = (const float*)d_in[8];
    const float* mnw   = (const float*)d_in[9];
    const float* mnb   = (const float*)d_in[10];
    const float* minw  = (const float*)d_in[11];
    const float* mcwp  = (const float*)d_in[12];
    const float* mcb   = (const float*)d_in[13];
    const float* mdtw  = (const float*)d_in[14];
    const float* mdtb  = (const float*)d_in[15];
    const float* mbw   = (const float*)d_in[16];
    const float* mcw2  = (const float*)d_in[17];
    const float* mD    = (const float*)d_in[18];
    const float* mAl   = (const float*)d_in[19];
    const float* mow   = (const float*)d_in[20];
    const float* al1w  = (const float*)d_in[21];
    const float* al1b  = (const float*)d_in[22];
    const float* aqkvw = (const float*)d_in[23];
    const float* aqkvb = (const float*)d_in[24];
    const float* aow   = (const float*)d_in[25];
    const float* aob   = (const float*)d_in[26];
    const float* al2w  = (const float*)d_in[27];
    const float* al2b  = (const float*)d_in[28];
    const float* af1w  = (const float*)d_in[29];
    const float* af1b  = (const float*)d_in[30];
    const float* af2w  = (const float*)d_in[31];
    const float* af2b  = (const float*)d_in[32];
    const float* hlnw  = (const float*)d_in[33];
    const float* hlnb  = (const float*)d_in[34];
    const float* hw    = (const float*)d_in[35];
    const float* hb    = (const float*)d_in[36];
    float* out = (float*)d_out;
    float* wsf = (float*)d_ws;
    if (ws_size < WS_FLOATS * sizeof(float)) return;

    float* x   = wsf + OFF_X;
    float* xn  = wsf + OFF_XN;
    float* xz  = wsf + OFF_XZ;   // also ff
    float* xc  = wsf + OFF_XC;   // also qkv (3M spans into DT arena)
    float* dtb = wsf + OFF_DT;
    float* yb  = wsf + OFF_Y;    // also attn_out
    float* bm  = wsf + OFF_BM;
    float* cm  = wsf + OFF_CM;
    float* sdb = wsf + OFF_SD;
    float* Fb  = wsf + OFF_F;
    float* Hsb = wsf + OFF_HS;
    float* qkv = xc;
    float* ff  = xz;
    float* aout = yb;

    embed_kernel<<<TOK, 128, 0, stream>>>(ids, tts, tstmp, emb, temb, tef, tep, tew, tebi, x);

    int mi = 0, ai = 0;
    for (int i = 0; i < 8; i++) {
        if ((i + 1) % 4 == 0) {
            // -------- attention layer --------
            ln_kernel<<<TOK / 4, 256, 0, stream>>>(x, al1w + ai * 128, al1b + ai * 128, xn);
            gemm_kernel<0, true, false><<<dim3(128, 6), 256, 0, stream>>>(
                xn, aqkvw + (size_t)ai * 384 * 128, aqkvb + ai * 384, qkv, TOK, 384, 128, 128, 384);
            attn_kernel<<<dim3(32, Hh, Bb), 256, 0, stream>>>(qkv, aout);
            gemm_kernel<0, true, true><<<dim3(128, 2), 256, 0, stream>>>(
                aout, aow + (size_t)ai * 128 * 128, aob + ai * 128, x, TOK, 128, 128, 128, 128);
            ln_kernel<<<TOK / 4, 256, 0, stream>>>(x, al2w + ai * 128, al2b + ai * 128, xn);
            gemm_kernel<2, true, false><<<dim3(128, 8), 256, 0, stream>>>(
                xn, af1w + (size_t)ai * 512 * 128, af1b + ai * 512, ff, TOK, 512, 128, 128, 512);
            gemm_kernel<0, true, true><<<dim3(128, 2), 256, 0, stream>>>(
                ff, af2w + (size_t)ai * 128 * 512, af2b + ai * 128, x, TOK, 128, 512, 512, 128);
            ai++;
        } else {
            // -------- mamba layer --------
            const float* Al = mAl + (size_t)mi * DIi * 16;
            ln_kernel<<<TOK / 4, 256, 0, stream>>>(x, mnw + mi * 128, mnb + mi * 128, xn);
            gemm_kernel<0, false, false><<<dim3(128, 8), 256, 0, stream>>>(
                xn, minw + (size_t)mi * 512 * 128, nullptr, xz, TOK, 512, 128, 128, 512);
            conv_kernel<<<8192, 256, 0, stream>>>(xz, mcwp + (size_t)mi * DIi * 4, mcb + mi * DIi, xc);
            gemm_kernel<1, true, false><<<dim3(128, 4), 256, 0, stream>>>(
                xc, mdtw + (size_t)mi * 256 * 256, mdtb + mi * 256, dtb, TOK, 256, 256, 256, 256);
            bc_kernel<<<512, 256, 0, stream>>>(xc, mbw + (size_t)mi * 16 * 256, mcw2 + (size_t)mi * 16 * 256, bm, cm);
            scan1_kernel<<<Bb * NC, 256, 0, stream>>>(dtb, xc, bm, Al, Fb, sdb);
            scan2_kernel<<<64, 256, 0, stream>>>(Fb, sdb, Al, Hsb);
            scan3_kernel<<<Bb * NC, 256, 0, stream>>>(dtb, xc, bm, cm, xz, Al, mD + mi * 256, Hsb, yb);
            gemm_kernel<0, false, true><<<dim3(128, 2), 256, 0, stream>>>(
                yb, mow + (size_t)mi * 128 * 256, nullptr, x, TOK, 128, 256, 256, 128);
            mi++;
        }
    }
    head_kernel<<<Bb, 128, 0, stream>>>(x, hlnw, hlnb, hw, hb, out);
}

// Round 2
// 1361.462 us; speedup vs baseline: 1.4434x; 1.4434x over previous
//
#include <hip/hip_runtime.h>
#include <hip/hip_bf16.h>
#include <math.h>

// ---- problem constants ----
constexpr int Ll = 2048, Bb = 4, DIi = 256, Hh = 4;
constexpr int TOK = Bb * Ll;       // 8192 tokens
constexpr int NC = 64;             // scan chunks per sequence
constexpr int CH = 32;             // chunk length (NC*CH = L)

#define DEV __device__ __forceinline__

DEV float siluf(float v)     { return v / (1.f + expf(-v)); }
DEV float softplusf(float v) { return (v > 20.f) ? v : log1pf(expf(v)); }
DEV float geluf(float v)     { return 0.5f * v * (1.f + erff(v * 0.7071067811865476f)); }

#if defined(__has_builtin)
#if __has_builtin(__builtin_amdgcn_exp2f)
#define EXP2F __builtin_amdgcn_exp2f
#endif
#endif
#ifndef EXP2F
#define EXP2F exp2f
#endif

// fp32 -> bf16 bits, round-to-nearest-even
DEV short f2bf(float f) {
    union { float f; unsigned u; } a; a.f = f;
    unsigned r = (a.u + 0x7fffu + ((a.u >> 16) & 1u)) >> 16;
    return (short)r;
}

using bf16x8 = __attribute__((ext_vector_type(8))) short;
using f32x4  = __attribute__((ext_vector_type(4))) float;

// ---------------- embedding ----------------
__global__ __launch_bounds__(128) void embed_kernel(
    const int* __restrict__ ids, const int* __restrict__ tts,
    const float* __restrict__ ts, const float* __restrict__ emb,
    const float* __restrict__ temb, const float* __restrict__ freqs,
    const float* __restrict__ phases, const float* __restrict__ tew,
    const float* __restrict__ teb, float* __restrict__ x)
{
    int tok = blockIdx.x;
    int d = threadIdx.x;
    __shared__ float enc[128];
    float tval = ts[tok];
    int j = d & 63;
    float a = tval * freqs[j] + phases[j];
    enc[d] = (d < 64) ? sinf(a) : cosf(a);
    __syncthreads();
    float acc = teb[d];
    const float* wrow = tew + (size_t)d * 128;
#pragma unroll 8
    for (int k = 0; k < 128; k++) acc += enc[k] * wrow[k];
    int id = ids[tok];
    int tt = tts[tok];
    x[(size_t)tok * 128 + d] = emb[(size_t)id * 128 + d] + temb[(size_t)tt * 128 + d] + acc;
}

// ---------------- layernorm (D=128), one wave per token ----------------
__global__ __launch_bounds__(256) void ln_kernel(
    const float* __restrict__ x, const float* __restrict__ w,
    const float* __restrict__ b, float* __restrict__ out)
{
    int wid = threadIdx.x >> 6, lane = threadIdx.x & 63;
    int tok = blockIdx.x * 4 + wid;
    const float* xr = x + (size_t)tok * 128;
    float2 v = *(const float2*)(xr + lane * 2);
    float s = v.x + v.y, sq = v.x * v.x + v.y * v.y;
#pragma unroll
    for (int o = 32; o > 0; o >>= 1) { s += __shfl_xor(s, o); sq += __shfl_xor(sq, o); }
    float mu = s * (1.f / 128.f);
    float var = sq * (1.f / 128.f) - mu * mu;
    float rstd = rsqrtf(var + 1e-5f);
    int d0 = lane * 2;
    out[(size_t)tok * 128 + d0]     = (v.x - mu) * rstd * w[d0]     + b[d0];
    out[(size_t)tok * 128 + d0 + 1] = (v.y - mu) * rstd * w[d0 + 1] + b[d0 + 1];
}

// ---------------- generic fp32 GEMM: C[M,N] = act(A[M,K] @ W[N,K].T + bias) ----------------
template <int ACT, bool BIAS, bool ADD>
__global__ __launch_bounds__(256) void gemm_kernel(
    const float* __restrict__ A, const float* __restrict__ W,
    const float* __restrict__ bias, float* __restrict__ C,
    int M, int N, int Kd, int lda, int ldc)
{
    __shared__ float As[16][68];
    __shared__ float Ws[16][68];
    int bm0 = blockIdx.x * 64, bn0 = blockIdx.y * 64;
    int tid = threadIdx.x;
    int ty = tid >> 4, tx = tid & 15;
    float acc[4][4] = {};
    int lr = tid >> 2;
    int kc = (tid & 3) << 2;
    for (int k0 = 0; k0 < Kd; k0 += 16) {
        float4 av = *(const float4*)(A + (size_t)(bm0 + lr) * lda + k0 + kc);
        float4 wv = *(const float4*)(W + (size_t)(bn0 + lr) * Kd + k0 + kc);
        As[kc][lr] = av.x; As[kc + 1][lr] = av.y; As[kc + 2][lr] = av.z; As[kc + 3][lr] = av.w;
        Ws[kc][lr] = wv.x; Ws[kc + 1][lr] = wv.y; Ws[kc + 2][lr] = wv.z; Ws[kc + 3][lr] = wv.w;
        __syncthreads();
#pragma unroll
        for (int k = 0; k < 16; k++) {
            float a[4], w[4];
            *(float4*)a = *(const float4*)&As[k][ty << 2];
            *(float4*)w = *(const float4*)&Ws[k][tx << 2];
#pragma unroll
            for (int i = 0; i < 4; i++)
#pragma unroll
                for (int j = 0; j < 4; j++) acc[i][j] += a[i] * w[j];
        }
        __syncthreads();
    }
#pragma unroll
    for (int i = 0; i < 4; i++) {
        int row = bm0 + (ty << 2) + i;
        int col = bn0 + (tx << 2);
        float v[4];
#pragma unroll
        for (int j = 0; j < 4; j++) {
            float t = acc[i][j];
            if (BIAS) t += bias[col + j];
            if (ACT == 1) t = softplusf(t);
            if (ACT == 2) t = geluf(t);
            v[j] = t;
        }
        float* p = C + (size_t)row * ldc + col;
        if (ADD) {
            float4 old = *(const float4*)p;
            v[0] += old.x; v[1] += old.y; v[2] += old.z; v[3] += old.w;
        }
        *(float4*)p = make_float4(v[0], v[1], v[2], v[3]);
    }
}

// ---------------- causal depthwise conv (K=4) + silu ----------------
__global__ __launch_bounds__(256) void conv_kernel(
    const float* __restrict__ xz, const float* __restrict__ cw,
    const float* __restrict__ cb, float* __restrict__ xc)
{
    int g = blockIdx.x * 256 + threadIdx.x;
    int c = g & 255;
    int t = (g >> 8) & 2047;
    int b = g >> 19;
    float4 w4 = *(const float4*)(cw + (size_t)c * 4);
    float acc = cb[c];
    const float* base = xz + ((size_t)b * 2048 + t) * 512 + c;
    if (t >= 3) {
        acc += base[-3 * 512] * w4.x + base[-2 * 512] * w4.y + base[-512] * w4.z + base[0] * w4.w;
    } else {
        const float wv[4] = {w4.x, w4.y, w4.z, w4.w};
#pragma unroll
        for (int kk = 0; kk < 4; kk++) {
            int tt = t - 3 + kk;
            if (tt >= 0) acc += xz[((size_t)b * 2048 + tt) * 512 + c] * wv[kk];
        }
    }
    xc[g] = siluf(acc);
}

// ---------------- B/C projections (N=16 each) ----------------
__global__ __launch_bounds__(256) void bc_kernel(
    const float* __restrict__ xc, const float* __restrict__ Bw,
    const float* __restrict__ Cw, float* __restrict__ bm, float* __restrict__ cm)
{
    __shared__ float xs[16][260];
    int t0 = blockIdx.x * 16;
    for (int idx = threadIdx.x; idx < 16 * 64; idx += 256) {
        int r = idx >> 6, c4 = (idx & 63) << 2;
        *(float4*)&xs[r][c4] = *(const float4*)(xc + (size_t)(t0 + r) * 256 + c4);
    }
    __syncthreads();
    int tk = threadIdx.x >> 4, j = threadIdx.x & 15;
    float accB = 0.f, accC = 0.f;
#pragma unroll 4
    for (int k = 0; k < 256; k += 4) {
        float xv[4], bw[4], cw[4];
        *(float4*)xv = *(const float4*)&xs[tk][k];
        *(float4*)bw = *(const float4*)(Bw + (size_t)j * 256 + k);
        *(float4*)cw = *(const float4*)(Cw + (size_t)j * 256 + k);
#pragma unroll
        for (int q = 0; q < 4; q++) { accB += xv[q] * bw[q]; accC += xv[q] * cw[q]; }
    }
    bm[(size_t)(t0 + tk) * 16 + j] = accB;
    cm[(size_t)(t0 + tk) * 16 + j] = accC;
}

// ---------------- scan phase 1 ----------------
__global__ __launch_bounds__(256) void scan1_kernel(
    const float* __restrict__ dt, const float* __restrict__ xc,
    const float* __restrict__ bm, const float* __restrict__ Alog,
    float* __restrict__ F, float* __restrict__ sumdt)
{
    int c = threadIdx.x;
    int k = blockIdx.x & (NC - 1);
    int b = blockIdx.x >> 6;
    __shared__ float sB[CH][16];
    int t0 = k * CH;
    if (threadIdx.x < CH * 4) {
        int r = threadIdx.x >> 2, c4 = (threadIdx.x & 3) << 2;
        *(float4*)&sB[r][c4] = *(const float4*)(bm + ((size_t)b * 2048 + t0 + r) * 16 + c4);
    }
    float A[16];
#pragma unroll
    for (int s = 0; s < 16; s++) A[s] = -expf(Alog[(size_t)c * 16 + s]);
    __syncthreads();
    float h[16] = {};
    float sd = 0.f;
    size_t base = ((size_t)b * 2048 + t0) * 256 + c;
    for (int tt = 0; tt < CH; tt++) {
        float d  = dt[base + (size_t)tt * 256];
        float xv = xc[base + (size_t)tt * 256];
        sd += d;
        float xdt = xv * d;
#pragma unroll
        for (int s = 0; s < 16; s++) h[s] = h[s] * expf(A[s] * d) + xdt * sB[tt][s];
    }
    size_t fo = (((size_t)b * NC + k) * 256 + c) * 16;
#pragma unroll
    for (int s = 0; s < 16; s += 4) *(float4*)(F + fo + s) = make_float4(h[s], h[s+1], h[s+2], h[s+3]);
    sumdt[((size_t)b * NC + k) * 256 + c] = sd;
}

// ---------------- scan phase 2 ----------------
__global__ __launch_bounds__(256) void scan2_kernel(
    const float* __restrict__ F, const float* __restrict__ sumdt,
    const float* __restrict__ Alog, float* __restrict__ Hs)
{
    int g = blockIdx.x * 256 + threadIdx.x;
    int s = g & 15, c = (g >> 4) & 255, b = g >> 12;
    float A = -expf(Alog[(size_t)c * 16 + s]);
    float h = 0.f;
    for (int k = 0; k < NC; k++) {
        size_t o = (((size_t)b * NC + k) * 256 + c) * 16 + s;
        Hs[o] = h;
        h = h * expf(A * sumdt[((size_t)b * NC + k) * 256 + c]) + F[o];
    }
}

// ---------------- scan phase 3 ----------------
__global__ __launch_bounds__(256) void scan3_kernel(
    const float* __restrict__ dt, const float* __restrict__ xc,
    const float* __restrict__ bm, const float* __restrict__ cm,
    const float* __restrict__ xz, const float* __restrict__ Alog,
    const float* __restrict__ Dp, const float* __restrict__ Hs,
    float* __restrict__ y)
{
    int c = threadIdx.x;
    int k = blockIdx.x & (NC - 1);
    int b = blockIdx.x >> 6;
    __shared__ float sB[CH][16], sC[CH][16];
    int t0 = k * CH;
    if (threadIdx.x < CH * 4) {
        int r = threadIdx.x >> 2, c4 = (threadIdx.x & 3) << 2;
        *(float4*)&sB[r][c4] = *(const float4*)(bm + ((size_t)b * 2048 + t0 + r) * 16 + c4);
        *(float4*)&sC[r][c4] = *(const float4*)(cm + ((size_t)b * 2048 + t0 + r) * 16 + c4);
    }
    float A[16];
#pragma unroll
    for (int s = 0; s < 16; s++) A[s] = -expf(Alog[(size_t)c * 16 + s]);
    __syncthreads();
    float h[16];
    size_t ho = (((size_t)b * NC + k) * 256 + c) * 16;
#pragma unroll
    for (int s = 0; s < 16; s++) h[s] = Hs[ho + s];
    float Dv = Dp[c];
    size_t base  = ((size_t)b * 2048 + t0) * 256 + c;
    size_t zbase = ((size_t)b * 2048 + t0) * 512 + 256 + c;
    for (int tt = 0; tt < CH; tt++) {
        float d  = dt[base + (size_t)tt * 256];
        float xv = xc[base + (size_t)tt * 256];
        float xdt = xv * d;
        float yv = 0.f;
#pragma unroll
        for (int s = 0; s < 16; s++) {
            h[s] = h[s] * expf(A[s] * d) + xdt * sB[tt][s];
            yv += h[s] * sC[tt][s];
        }
        yv += xv * Dv;
        float zv = xz[zbase + (size_t)tt * 512];
        y[base + (size_t)tt * 256] = yv * siluf(zv);
    }
}

// ---------------- qkv prep: K -> bf16 [b,h,k,d], V -> bf16 transposed [b,h,d,k] ----------------
__global__ __launch_bounds__(256) void qkv_prep_kernel(
    const float* __restrict__ qkv, short* __restrict__ kbf, short* __restrict__ vbf)
{
    int tt = blockIdx.x, h = blockIdx.y, b = blockIdx.z;   // tt: 64-token tile
    __shared__ float Vs[64][33];
    int tid = threadIdx.x;
    int t0 = tt * 64;
    int tl = tid >> 2, dg = (tid & 3) * 8;
    const float* kp = qkv + ((size_t)(b * 2048 + t0 + tl)) * 384 + 128 + 32 * h + dg;
    const float* vp = kp + 128;
    float kf[8], vf[8];
    *(float4*)kf       = *(const float4*)kp;
    *(float4*)(kf + 4) = *(const float4*)(kp + 4);
    *(float4*)vf       = *(const float4*)vp;
    *(float4*)(vf + 4) = *(const float4*)(vp + 4);
    bf16x8 ko;
#pragma unroll
    for (int j = 0; j < 8; j++) { ko[j] = f2bf(kf[j]); Vs[tl][dg + j] = vf[j]; }
    *(bf16x8*)(kbf + (((size_t)(b * 4 + h) * 2048) + t0 + tl) * 32 + dg) = ko;
    __syncthreads();
    int d = tid >> 3, tc = (tid & 7) * 8;
    bf16x8 vo;
#pragma unroll
    for (int j = 0; j < 8; j++) vo[j] = f2bf(Vs[tc + j][d]);
    *(bf16x8*)(vbf + ((size_t)(b * 4 + h) * 32 + d) * 2048 + t0 + tc) = vo;
}

// ---------------- bf16 MFMA flash attention ----------------
// block = 4 waves; wave w handles 16 q rows. Swapped QK^T: S^T = mfma(K, Q);
// per-lane q column => softmax reductions via shfl_xor(16/32). PV: O^T = mfma(V^T, P^T)
// with P^T via per-wave LDS round-trip. K/V read as bf16 (prep kernel), 16B/lane.
__global__ __launch_bounds__(256) void attn_mfma_kernel(
    const float* __restrict__ qkv, const short* __restrict__ kbf,
    const short* __restrict__ vbf, float* __restrict__ o_out)
{
    __shared__ short Pt[4][64][18];       // per-wave P^T [k][q], stride 18 kills conflicts
    const int qt = blockIdx.x, h = blockIdx.y, b = blockIdx.z;
    const int tid = threadIdx.x;
    const int w = tid >> 6, l = tid & 63;
    const int q16 = l & 15, g = l >> 4;
    const float cQ = 0.25503634043f;      // log2(e)/sqrt(32): softmax in exp2 domain

    const int qrow = qt * 64 + w * 16 + q16;
    const float* qp = qkv + ((size_t)(b * 2048 + qrow)) * 384 + 32 * h + g * 8;
    bf16x8 qfrag;
    {
        float qf[8];
        *(float4*)qf       = *(const float4*)qp;
        *(float4*)(qf + 4) = *(const float4*)(qp + 4);
#pragma unroll
        for (int i = 0; i < 8; i++) qfrag[i] = f2bf(qf[i] * cQ);
    }
    const short* kb = kbf + ((size_t)(b * 4 + h) * 2048) * 32;  // [k][d]
    const short* vb = vbf + ((size_t)(b * 4 + h) * 32) * 2048;  // [d][k]

    float m = -1e30f, lsum = 0.f;
    f32x4 O0 = {0.f, 0.f, 0.f, 0.f}, O1 = {0.f, 0.f, 0.f, 0.f};
    const f32x4 zf = {0.f, 0.f, 0.f, 0.f};

    auto ldKV = [&](bf16x8 (&kf)[4], bf16x8 (&vf)[4], int t) {
#pragma unroll
        for (int kt = 0; kt < 4; kt++)
            kf[kt] = *(const bf16x8*)(kb + (size_t)(t * 64 + kt * 16 + q16) * 32 + g * 8);
#pragma unroll
        for (int c = 0; c < 2; c++)
#pragma unroll
            for (int hf = 0; hf < 2; hf++)
                vf[c * 2 + hf] = *(const bf16x8*)(vb + (size_t)(q16 + 16 * hf) * 2048 + t * 64 + 32 * c + g * 8);
    };

    auto step = [&](bf16x8 (&kf)[4], bf16x8 (&vf)[4]) {
        f32x4 St[4];
#pragma unroll
        for (int kt = 0; kt < 4; kt++)
            St[kt] = __builtin_amdgcn_mfma_f32_16x16x32_bf16(kf[kt], qfrag, zf, 0, 0, 0);
        // online softmax (lane owns one q column; 16 keys per lane in regs)
        float pm = St[0][0];
#pragma unroll
        for (int kt = 0; kt < 4; kt++)
#pragma unroll
            for (int r = 0; r < 4; r++) pm = fmaxf(pm, St[kt][r]);
        pm = fmaxf(pm, __shfl_xor(pm, 16));
        pm = fmaxf(pm, __shfl_xor(pm, 32));
        float mn = fmaxf(m, pm);
        float rs = EXP2F(m - mn);
        float ps = 0.f;
#pragma unroll
        for (int kt = 0; kt < 4; kt++)
#pragma unroll
            for (int r = 0; r < 4; r++) {
                float p = EXP2F(St[kt][r] - mn);
                ps += p;
                Pt[w][kt * 16 + g * 4 + r][q16] = f2bf(p);
            }
        ps += __shfl_xor(ps, 16);
        ps += __shfl_xor(ps, 32);
        lsum = lsum * rs + ps;
        m = mn;
        O0 *= rs; O1 *= rs;
        // PV: O^T[d][q] += V^T[d][k] * P^T[k][q]
#pragma unroll
        for (int c = 0; c < 2; c++) {
            bf16x8 pb;
#pragma unroll
            for (int i = 0; i < 8; i++) pb[i] = Pt[w][c * 32 + g * 8 + i][q16];
            O0 = __builtin_amdgcn_mfma_f32_16x16x32_bf16(vf[c * 2 + 0], pb, O0, 0, 0, 0);
            O1 = __builtin_amdgcn_mfma_f32_16x16x32_bf16(vf[c * 2 + 1], pb, O1, 0, 0, 0);
        }
    };

    bf16x8 kA[4], kB[4], vA[4], vB[4];
    ldKV(kA, vA, 0);
    for (int t = 0; t < 32; t += 2) {
        if (t + 1 < 32) ldKV(kB, vB, t + 1);
        step(kA, vA);
        if (t + 2 < 32) ldKV(kA, vA, t + 2);
        step(kB, vB);
    }

    float inv = 1.f / lsum;
    float* op = o_out + ((size_t)(b * 2048 + qrow)) * 128 + 32 * h;
#pragma unroll
    for (int r = 0; r < 4; r++) {
        op[g * 4 + r]      = O0[r] * inv;   // d = 4g + r
        op[16 + g * 4 + r] = O1[r] * inv;   // d = 16 + 4g + r
    }
}

// ---------------- head ----------------
__global__ __launch_bounds__(128) void head_kernel(
    const float* __restrict__ x, const float* __restrict__ w,
    const float* __restrict__ bsp, const float* __restrict__ hw,
    const float* __restrict__ hb, float* __restrict__ out)
{
    int bb = blockIdx.x;
    int d = threadIdx.x;
    int wid = d >> 6, lane = d & 63;
    float v = x[(size_t)bb * 2048 * 128 + d];
    float s = v, sq = v * v;
#pragma unroll
    for (int o = 32; o > 0; o >>= 1) { s += __shfl_xor(s, o); sq += __shfl_xor(sq, o); }
    __shared__ float red[4];
    if (lane == 0) { red[wid] = s; red[2 + wid] = sq; }
    __syncthreads();
    s = red[0] + red[1]; sq = red[2] + red[3];
    float mu = s * (1.f / 128.f);
    float var = sq * (1.f / 128.f) - mu * mu;
    float xn = (v - mu) * rsqrtf(var + 1e-5f) * w[d] + bsp[d];
    float pr = xn * hw[d];
#pragma unroll
    for (int o = 32; o > 0; o >>= 1) pr += __shfl_xor(pr, o);
    __syncthreads();
    if (lane == 0) red[wid] = pr;
    __syncthreads();
    if (d == 0) out[bb] = red[0] + red[1] + hb[0];
}

// ---------------- workspace layout (floats) ----------------
constexpr size_t OFF_X  = 0;
constexpr size_t OFF_XN = (size_t)1 << 20;
constexpr size_t OFF_XZ = (size_t)2 << 20;
constexpr size_t OFF_XC = (size_t)6 << 20;
constexpr size_t OFF_DT = (size_t)8 << 20;
constexpr size_t OFF_Y  = (size_t)10 << 20;
constexpr size_t OFF_BM = (size_t)12 << 20;
constexpr size_t OFF_CM = OFF_BM + 131072;
constexpr size_t OFF_SD = OFF_CM + 131072;
constexpr size_t OFF_F  = OFF_SD + 65536;            // 1M floats (mamba) / kbf bf16 (attn)
constexpr size_t OFF_HS = OFF_F + ((size_t)1 << 20); // 1M floats (mamba) / vbf bf16 (attn)
constexpr size_t WS_FLOATS = OFF_HS + ((size_t)1 << 20);

extern "C" void kernel_launch(void* const* d_in, const int* in_sizes, int n_in,
                              void* d_out, int out_size, void* d_ws, size_t ws_size,
                              hipStream_t stream)
{
    const int*   ids   = (const int*)d_in[0];
    const int*   tts   = (const int*)d_in[1];
    const float* tstmp = (const float*)d_in[2];
    const float* emb   = (const float*)d_in[3];
    const float* temb  = (const float*)d_in[4];
    const float* tef   = (const float*)d_in[5];
    const float* tep   = (const float*)d_in[6];
    const float* tew   = (const float*)d_in[7];
    const float* tebi  = (const float*)d_in[8];
    const float* mnw   = (const float*)d_in[9];
    const float* mnb   = (const float*)d_in[10];
    const float* minw  = (const float*)d_in[11];
    const float* mcwp  = (const float*)d_in[12];
    const float* mcb   = (const float*)d_in[13];
    const float* mdtw  = (const float*)d_in[14];
    const float* mdtb  = (const float*)d_in[15];
    const float* mbw   = (const float*)d_in[16];
    const float* mcw2  = (const float*)d_in[17];
    const float* mD    = (const float*)d_in[18];
    const float* mAl   = (const float*)d_in[19];
    const float* mow   = (const float*)d_in[20];
    const float* al1w  = (const float*)d_in[21];
    const float* al1b  = (const float*)d_in[22];
    const float* aqkvw = (const float*)d_in[23];
    const float* aqkvb = (const float*)d_in[24];
    const float* aow   = (const float*)d_in[25];
    const float* aob   = (const float*)d_in[26];
    const float* al2w  = (const float*)d_in[27];
    const float* al2b  = (const float*)d_in[28];
    const float* af1w  = (const float*)d_in[29];
    const float* af1b  = (const float*)d_in[30];
    const float* af2w  = (const float*)d_in[31];
    const float* af2b  = (const float*)d_in[32];
    const float* hlnw  = (const float*)d_in[33];
    const float* hlnb  = (const float*)d_in[34];
    const float* hw    = (const float*)d_in[35];
    const float* hb    = (const float*)d_in[36];
    float* out = (float*)d_out;
    float* wsf = (float*)d_ws;
    if (ws_size < WS_FLOATS * sizeof(float)) return;

    float* x   = wsf + OFF_X;
    float* xn  = wsf + OFF_XN;
    float* xz  = wsf + OFF_XZ;
    float* xc  = wsf + OFF_XC;
    float* dtb = wsf + OFF_DT;
    float* yb  = wsf + OFF_Y;
    float* bm  = wsf + OFF_BM;
    float* cm  = wsf + OFF_CM;
    float* sdb = wsf + OFF_SD;
    float* Fb  = wsf + OFF_F;
    float* Hsb = wsf + OFF_HS;
    float* qkv = xc;
    float* ff  = xz;
    float* aout = yb;
    short* kbf = (short*)(wsf + OFF_F);   // mamba-only regions reused during attention
    short* vbf = (short*)(wsf + OFF_HS);

    embed_kernel<<<TOK, 128, 0, stream>>>(ids, tts, tstmp, emb, temb, tef, tep, tew, tebi, x);

    int mi = 0, ai = 0;
    for (int i = 0; i < 8; i++) {
        if ((i + 1) % 4 == 0) {
            // -------- attention layer --------
            ln_kernel<<<TOK / 4, 256, 0, stream>>>(x, al1w + ai * 128, al1b + ai * 128, xn);
            gemm_kernel<0, true, false><<<dim3(128, 6), 256, 0, stream>>>(
                xn, aqkvw + (size_t)ai * 384 * 128, aqkvb + ai * 384, qkv, TOK, 384, 128, 128, 384);
            qkv_prep_kernel<<<dim3(32, Hh, Bb), 256, 0, stream>>>(qkv, kbf, vbf);
            attn_mfma_kernel<<<dim3(32, Hh, Bb), 256, 0, stream>>>(qkv, kbf, vbf, aout);
            gemm_kernel<0, true, true><<<dim3(128, 2), 256, 0, stream>>>(
                aout, aow + (size_t)ai * 128 * 128, aob + ai * 128, x, TOK, 128, 128, 128, 128);
            ln_kernel<<<TOK / 4, 256, 0, stream>>>(x, al2w + ai * 128, al2b + ai * 128, xn);
            gemm_kernel<2, true, false><<<dim3(128, 8), 256, 0, stream>>>(
                xn, af1w + (size_t)ai * 512 * 128, af1b + ai * 512, ff, TOK, 512, 128, 128, 512);
            gemm_kernel<0, true, true><<<dim3(128, 2), 256, 0, stream>>>(
                ff, af2w + (size_t)ai * 128 * 512, af2b + ai * 128, x, TOK, 128, 512, 512, 128);
            ai++;
        } else {
            // -------- mamba layer --------
            const float* Al = mAl + (size_t)mi * DIi * 16;
            ln_kernel<<<TOK / 4, 256, 0, stream>>>(x, mnw + mi * 128, mnb + mi * 128, xn);
            gemm_kernel<0, false, false><<<dim3(128, 8), 256, 0, stream>>>(
                xn, minw + (size_t)mi * 512 * 128, nullptr, xz, TOK, 512, 128, 128, 512);
            conv_kernel<<<8192, 256, 0, stream>>>(xz, mcwp + (size_t)mi * DIi * 4, mcb + mi * DIi, xc);
            gemm_kernel<1, true, false><<<dim3(128, 4), 256, 0, stream>>>(
                xc, mdtw + (size_t)mi * 256 * 256, mdtb + mi * 256, dtb, TOK, 256, 256, 256, 256);
            bc_kernel<<<512, 256, 0, stream>>>(xc, mbw + (size_t)mi * 16 * 256, mcw2 + (size_t)mi * 16 * 256, bm, cm);
            scan1_kernel<<<Bb * NC, 256, 0, stream>>>(dtb, xc, bm, Al, Fb, sdb);
            scan2_kernel<<<64, 256, 0, stream>>>(Fb, sdb, Al, Hsb);
            scan3_kernel<<<Bb * NC, 256, 0, stream>>>(dtb, xc, bm, cm, xz, Al, mD + mi * 256, Hsb, yb);
            gemm_kernel<0, false, true><<<dim3(128, 2), 256, 0, stream>>>(
                yb, mow + (size_t)mi * 128 * 256, nullptr, x, TOK, 128, 256, 256, 128);
            mi++;
        }
    }
    head_kernel<<<Bb, 128, 0, stream>>>(x, hlnw, hlnb, hw, hb, out);
}

// Round 4
// 1091.116 us; speedup vs baseline: 1.8011x; 1.2478x over previous
//
#include <hip/hip_runtime.h>
#include <hip/hip_bf16.h>
#include <math.h>

// ---- problem constants ----
constexpr int Ll = 2048, Bb = 4, DIi = 256, Hh = 4;
constexpr int TOK = Bb * Ll;       // 8192 tokens
constexpr int NC = 64;             // scan chunks per sequence
constexpr int CH = 32;             // chunk length (NC*CH = L)

#define DEV __device__ __forceinline__

DEV float siluf(float v)     { return v / (1.f + expf(-v)); }
DEV float softplusf(float v) { return (v > 20.f) ? v : log1pf(expf(v)); }
DEV float geluf(float v)     { return 0.5f * v * (1.f + erff(v * 0.7071067811865476f)); }

#if defined(__has_builtin)
#if __has_builtin(__builtin_amdgcn_exp2f)
#define EXP2F __builtin_amdgcn_exp2f
#endif
#endif
#ifndef EXP2F
#define EXP2F exp2f
#endif

// fp32 -> bf16 bits, round-to-nearest-even (attention only)
DEV short f2bf(float f) {
    union { float f; unsigned u; } a; a.f = f;
    unsigned r = (a.u + 0x7fffu + ((a.u >> 16) & 1u)) >> 16;
    return (short)r;
}

using bf16x8 = __attribute__((ext_vector_type(8))) short;
using f16x8  = __attribute__((ext_vector_type(8))) _Float16;
using f32x4  = __attribute__((ext_vector_type(4))) float;

// ---------------- gather + time encoding ----------------
__global__ __launch_bounds__(256) void gather_enc_kernel(
    const int* __restrict__ ids, const int* __restrict__ tts,
    const float* __restrict__ ts, const float* __restrict__ emb,
    const float* __restrict__ temb, const float* __restrict__ freqs,
    const float* __restrict__ phases, float* __restrict__ x,
    float* __restrict__ enc)
{
    int tok = blockIdx.x * 2 + (threadIdx.x >> 7);
    int d = threadIdx.x & 127;
    float tval = ts[tok];
    int j = d & 63;
    float a = tval * freqs[j] + phases[j];
    enc[(size_t)tok * 128 + d] = (d < 64) ? sinf(a) : cosf(a);
    int id = ids[tok];
    int tt = tts[tok];
    x[(size_t)tok * 128 + d] = emb[(size_t)id * 128 + d] + temb[(size_t)tt * 128 + d];
}

// ---------------- layernorm (D=128), one wave per token ----------------
__global__ __launch_bounds__(256) void ln_kernel(
    const float* __restrict__ x, const float* __restrict__ w,
    const float* __restrict__ b, float* __restrict__ out)
{
    int wid = threadIdx.x >> 6, lane = threadIdx.x & 63;
    int tok = blockIdx.x * 4 + wid;
    const float* xr = x + (size_t)tok * 128;
    float2 v = *(const float2*)(xr + lane * 2);
    float s = v.x + v.y, sq = v.x * v.x + v.y * v.y;
#pragma unroll
    for (int o = 32; o > 0; o >>= 1) { s += __shfl_xor(s, o); sq += __shfl_xor(sq, o); }
    float mu = s * (1.f / 128.f);
    float var = sq * (1.f / 128.f) - mu * mu;
    float rstd = rsqrtf(var + 1e-5f);
    int d0 = lane * 2;
    out[(size_t)tok * 128 + d0]     = (v.x - mu) * rstd * w[d0]     + b[d0];
    out[(size_t)tok * 128 + d0 + 1] = (v.y - mu) * rstd * w[d0 + 1] + b[d0 + 1];
}

// ---------------- f16 MFMA GEMM: C[M,N] = act(A[M,K] @ W[N,K].T + bias) ----------------
// BM=BN=64, BK=64. 256 threads = 4 waves (2x2), each wave a 32x32 quadrant.
// fp32 inputs converted to f16 (10-bit mantissa: 8x tighter than bf16) during LDS
// staging; f32 accumulate; fp32 epilogue.
template <int ACT, bool BIAS, bool ADD>
__global__ __launch_bounds__(256) void gemm_f16_kernel(
    const float* __restrict__ A, const float* __restrict__ W,
    const float* __restrict__ bias, float* __restrict__ C,
    int M, int N, int Kd, int lda, int ldc)
{
    __shared__ _Float16 As[64][72];   // 144B row stride: 2-way bank aliasing max (free)
    __shared__ _Float16 Ws[64][72];
    const int bm0 = blockIdx.x * 64, bn0 = blockIdx.y * 64;
    const int tid = threadIdx.x;
    const int w = tid >> 6, l = tid & 63;
    const int wr = w >> 1, wc = w & 1;           // wave 2x2 grid
    const int fr = l & 15, fk = (l >> 4) * 8;    // fragment lane mapping
    const int srow = tid >> 2, skc = (tid & 3) * 16;  // staging row / k-chunk
    f32x4 acc[2][2] = {};

    for (int k0 = 0; k0 < Kd; k0 += 64) {
        const float* ap = A + (size_t)(bm0 + srow) * lda + k0 + skc;
        const float* wp = W + (size_t)(bn0 + srow) * Kd + k0 + skc;
        float af[16], wf[16];
#pragma unroll
        for (int q = 0; q < 4; q++) {
            *(float4*)(af + q * 4) = *(const float4*)(ap + q * 4);
            *(float4*)(wf + q * 4) = *(const float4*)(wp + q * 4);
        }
        f16x8 ab0, ab1, wb0, wb1;
#pragma unroll
        for (int q = 0; q < 8; q++) {
            ab0[q] = (_Float16)af[q]; ab1[q] = (_Float16)af[q + 8];
            wb0[q] = (_Float16)wf[q]; wb1[q] = (_Float16)wf[q + 8];
        }
        __syncthreads();   // previous iteration's reads complete
        *(f16x8*)&As[srow][skc]     = ab0;
        *(f16x8*)&As[srow][skc + 8] = ab1;
        *(f16x8*)&Ws[srow][skc]     = wb0;
        *(f16x8*)&Ws[srow][skc + 8] = wb1;
        __syncthreads();
#pragma unroll
        for (int ks = 0; ks < 64; ks += 32) {
            f16x8 afr0 = *(const f16x8*)&As[wr * 32 + fr][ks + fk];
            f16x8 afr1 = *(const f16x8*)&As[wr * 32 + 16 + fr][ks + fk];
            f16x8 wfr0 = *(const f16x8*)&Ws[wc * 32 + fr][ks + fk];
            f16x8 wfr1 = *(const f16x8*)&Ws[wc * 32 + 16 + fr][ks + fk];
            acc[0][0] = __builtin_amdgcn_mfma_f32_16x16x32_f16(afr0, wfr0, acc[0][0], 0, 0, 0);
            acc[0][1] = __builtin_amdgcn_mfma_f32_16x16x32_f16(afr0, wfr1, acc[0][1], 0, 0, 0);
            acc[1][0] = __builtin_amdgcn_mfma_f32_16x16x32_f16(afr1, wfr0, acc[1][0], 0, 0, 0);
            acc[1][1] = __builtin_amdgcn_mfma_f32_16x16x32_f16(afr1, wfr1, acc[1][1], 0, 0, 0);
        }
    }
    // epilogue: C row = (l>>4)*4 + reg (A-side m), col = l&15 (W-side n)
#pragma unroll
    for (int ri = 0; ri < 2; ri++)
#pragma unroll
    for (int ci = 0; ci < 2; ci++) {
        int col = bn0 + wc * 32 + ci * 16 + fr;
        float bv = BIAS ? bias[col] : 0.f;
#pragma unroll
        for (int r = 0; r < 4; r++) {
            int row = bm0 + wr * 32 + ri * 16 + (l >> 4) * 4 + r;
            float t = acc[ri][ci][r] + bv;
            if (ACT == 1) t = softplusf(t);
            if (ACT == 2) t = geluf(t);
            float* p = C + (size_t)row * ldc + col;
            if (ADD) t += *p;
            *p = t;
        }
    }
}

// ---------------- causal depthwise conv (K=4) + silu ----------------
__global__ __launch_bounds__(256) void conv_kernel(
    const float* __restrict__ xz, const float* __restrict__ cw,
    const float* __restrict__ cb, float* __restrict__ xc)
{
    int g = blockIdx.x * 256 + threadIdx.x;
    int c = g & 255;
    int t = (g >> 8) & 2047;
    int b = g >> 19;
    float4 w4 = *(const float4*)(cw + (size_t)c * 4);
    float acc = cb[c];
    const float* base = xz + ((size_t)b * 2048 + t) * 512 + c;
    if (t >= 3) {
        acc += base[-3 * 512] * w4.x + base[-2 * 512] * w4.y + base[-512] * w4.z + base[0] * w4.w;
    } else {
        const float wv[4] = {w4.x, w4.y, w4.z, w4.w};
#pragma unroll
        for (int kk = 0; kk < 4; kk++) {
            int tt = t - 3 + kk;
            if (tt >= 0) acc += xz[((size_t)b * 2048 + tt) * 512 + c] * wv[kk];
        }
    }
    xc[g] = siluf(acc);
}

// ---------------- B/C projections (N=16 each) ----------------
__global__ __launch_bounds__(256) void bc_kernel(
    const float* __restrict__ xc, const float* __restrict__ Bw,
    const float* __restrict__ Cw, float* __restrict__ bm, float* __restrict__ cm)
{
    __shared__ float xs[16][260];
    int t0 = blockIdx.x * 16;
    for (int idx = threadIdx.x; idx < 16 * 64; idx += 256) {
        int r = idx >> 6, c4 = (idx & 63) << 2;
        *(float4*)&xs[r][c4] = *(const float4*)(xc + (size_t)(t0 + r) * 256 + c4);
    }
    __syncthreads();
    int tk = threadIdx.x >> 4, j = threadIdx.x & 15;
    float accB = 0.f, accC = 0.f;
#pragma unroll 4
    for (int k = 0; k < 256; k += 4) {
        float xv[4], bw[4], cw[4];
        *(float4*)xv = *(const float4*)&xs[tk][k];
        *(float4*)bw = *(const float4*)(Bw + (size_t)j * 256 + k);
        *(float4*)cw = *(const float4*)(Cw + (size_t)j * 256 + k);
#pragma unroll
        for (int q = 0; q < 4; q++) { accB += xv[q] * bw[q]; accC += xv[q] * cw[q]; }
    }
    bm[(size_t)(t0 + tk) * 16 + j] = accB;
    cm[(size_t)(t0 + tk) * 16 + j] = accC;
}

// ---------------- scan phase 1 ----------------
__global__ __launch_bounds__(256) void scan1_kernel(
    const float* __restrict__ dt, const float* __restrict__ xc,
    const float* __restrict__ bm, const float* __restrict__ Alog,
    float* __restrict__ F, float* __restrict__ sumdt)
{
    int c = threadIdx.x;
    int k = blockIdx.x & (NC - 1);
    int b = blockIdx.x >> 6;
    __shared__ float sB[CH][16];
    int t0 = k * CH;
    if (threadIdx.x < CH * 4) {
        int r = threadIdx.x >> 2, c4 = (threadIdx.x & 3) << 2;
        *(float4*)&sB[r][c4] = *(const float4*)(bm + ((size_t)b * 2048 + t0 + r) * 16 + c4);
    }
    float A[16];
#pragma unroll
    for (int s = 0; s < 16; s++) A[s] = -expf(Alog[(size_t)c * 16 + s]);
    __syncthreads();
    float h[16] = {};
    float sd = 0.f;
    size_t base = ((size_t)b * 2048 + t0) * 256 + c;
    for (int tt = 0; tt < CH; tt++) {
        float d  = dt[base + (size_t)tt * 256];
        float xv = xc[base + (size_t)tt * 256];
        sd += d;
        float xdt = xv * d;
#pragma unroll
        for (int s = 0; s < 16; s++) h[s] = h[s] * expf(A[s] * d) + xdt * sB[tt][s];
    }
    size_t fo = (((size_t)b * NC + k) * 256 + c) * 16;
#pragma unroll
    for (int s = 0; s < 16; s += 4) *(float4*)(F + fo + s) = make_float4(h[s], h[s+1], h[s+2], h[s+3]);
    sumdt[((size_t)b * NC + k) * 256 + c] = sd;
}

// ---------------- scan phase 2 ----------------
__global__ __launch_bounds__(256) void scan2_kernel(
    const float* __restrict__ F, const float* __restrict__ sumdt,
    const float* __restrict__ Alog, float* __restrict__ Hs)
{
    int g = blockIdx.x * 256 + threadIdx.x;
    int s = g & 15, c = (g >> 4) & 255, b = g >> 12;
    float A = -expf(Alog[(size_t)c * 16 + s]);
    float h = 0.f;
    for (int k = 0; k < NC; k++) {
        size_t o = (((size_t)b * NC + k) * 256 + c) * 16 + s;
        Hs[o] = h;
        h = h * expf(A * sumdt[((size_t)b * NC + k) * 256 + c]) + F[o];
    }
}

// ---------------- scan phase 3 ----------------
__global__ __launch_bounds__(256) void scan3_kernel(
    const float* __restrict__ dt, const float* __restrict__ xc,
    const float* __restrict__ bm, const float* __restrict__ cm,
    const float* __restrict__ xz, const float* __restrict__ Alog,
    const float* __restrict__ Dp, const float* __restrict__ Hs,
    float* __restrict__ y)
{
    int c = threadIdx.x;
    int k = blockIdx.x & (NC - 1);
    int b = blockIdx.x >> 6;
    __shared__ float sB[CH][16], sC[CH][16];
    int t0 = k * CH;
    if (threadIdx.x < CH * 4) {
        int r = threadIdx.x >> 2, c4 = (threadIdx.x & 3) << 2;
        *(float4*)&sB[r][c4] = *(const float4*)(bm + ((size_t)b * 2048 + t0 + r) * 16 + c4);
        *(float4*)&sC[r][c4] = *(const float4*)(cm + ((size_t)b * 2048 + t0 + r) * 16 + c4);
    }
    float A[16];
#pragma unroll
    for (int s = 0; s < 16; s++) A[s] = -expf(Alog[(size_t)c * 16 + s]);
    __syncthreads();
    float h[16];
    size_t ho = (((size_t)b * NC + k) * 256 + c) * 16;
#pragma unroll
    for (int s = 0; s < 16; s++) h[s] = Hs[ho + s];
    float Dv = Dp[c];
    size_t base  = ((size_t)b * 2048 + t0) * 256 + c;
    size_t zbase = ((size_t)b * 2048 + t0) * 512 + 256 + c;
    for (int tt = 0; tt < CH; tt++) {
        float d  = dt[base + (size_t)tt * 256];
        float xv = xc[base + (size_t)tt * 256];
        float xdt = xv * d;
        float yv = 0.f;
#pragma unroll
        for (int s = 0; s < 16; s++) {
            h[s] = h[s] * expf(A[s] * d) + xdt * sB[tt][s];
            yv += h[s] * sC[tt][s];
        }
        yv += xv * Dv;
        float zv = xz[zbase + (size_t)tt * 512];
        y[base + (size_t)tt * 256] = yv * siluf(zv);
    }
}

// ---------------- qkv prep: K -> bf16 [b,h,k,d], V -> bf16 transposed [b,h,d,k] ----------------
__global__ __launch_bounds__(256) void qkv_prep_kernel(
    const float* __restrict__ qkv, short* __restrict__ kbf, short* __restrict__ vbf)
{
    int tt = blockIdx.x, h = blockIdx.y, b = blockIdx.z;
    __shared__ float Vs[64][33];
    int tid = threadIdx.x;
    int t0 = tt * 64;
    int tl = tid >> 2, dg = (tid & 3) * 8;
    const float* kp = qkv + ((size_t)(b * 2048 + t0 + tl)) * 384 + 128 + 32 * h + dg;
    const float* vp = kp + 128;
    float kf[8], vf[8];
    *(float4*)kf       = *(const float4*)kp;
    *(float4*)(kf + 4) = *(const float4*)(kp + 4);
    *(float4*)vf       = *(const float4*)vp;
    *(float4*)(vf + 4) = *(const float4*)(vp + 4);
    bf16x8 ko;
#pragma unroll
    for (int j = 0; j < 8; j++) { ko[j] = f2bf(kf[j]); Vs[tl][dg + j] = vf[j]; }
    *(bf16x8*)(kbf + (((size_t)(b * 4 + h) * 2048) + t0 + tl) * 32 + dg) = ko;
    __syncthreads();
    int d = tid >> 3, tc = (tid & 7) * 8;
    bf16x8 vo;
#pragma unroll
    for (int j = 0; j < 8; j++) vo[j] = f2bf(Vs[tc + j][d]);
    *(bf16x8*)(vbf + ((size_t)(b * 4 + h) * 32 + d) * 2048 + t0 + tc) = vo;
}

// ---------------- bf16 MFMA flash attention ----------------
__global__ __launch_bounds__(256) void attn_mfma_kernel(
    const float* __restrict__ qkv, const short* __restrict__ kbf,
    const short* __restrict__ vbf, float* __restrict__ o_out)
{
    __shared__ short Pt[4][64][18];
    const int qt = blockIdx.x, h = blockIdx.y, b = blockIdx.z;
    const int tid = threadIdx.x;
    const int w = tid >> 6, l = tid & 63;
    const int q16 = l & 15, g = l >> 4;
    const float cQ = 0.25503634043f;      // log2(e)/sqrt(32)

    const int qrow = qt * 64 + w * 16 + q16;
    const float* qp = qkv + ((size_t)(b * 2048 + qrow)) * 384 + 32 * h + g * 8;
    bf16x8 qfrag;
    {
        float qf[8];
        *(float4*)qf       = *(const float4*)qp;
        *(float4*)(qf + 4) = *(const float4*)(qp + 4);
#pragma unroll
        for (int i = 0; i < 8; i++) qfrag[i] = f2bf(qf[i] * cQ);
    }
    const short* kb = kbf + ((size_t)(b * 4 + h) * 2048) * 32;
    const short* vb = vbf + ((size_t)(b * 4 + h) * 32) * 2048;

    float m = -1e30f, lsum = 0.f;
    f32x4 O0 = {0.f, 0.f, 0.f, 0.f}, O1 = {0.f, 0.f, 0.f, 0.f};
    const f32x4 zf = {0.f, 0.f, 0.f, 0.f};

    auto ldKV = [&](bf16x8 (&kf)[4], bf16x8 (&vf)[4], int t) {
#pragma unroll
        for (int kt = 0; kt < 4; kt++)
            kf[kt] = *(const bf16x8*)(kb + (size_t)(t * 64 + kt * 16 + q16) * 32 + g * 8);
#pragma unroll
        for (int c = 0; c < 2; c++)
#pragma unroll
            for (int hf = 0; hf < 2; hf++)
                vf[c * 2 + hf] = *(const bf16x8*)(vb + (size_t)(q16 + 16 * hf) * 2048 + t * 64 + 32 * c + g * 8);
    };

    auto step = [&](bf16x8 (&kf)[4], bf16x8 (&vf)[4]) {
        f32x4 St[4];
#pragma unroll
        for (int kt = 0; kt < 4; kt++)
            St[kt] = __builtin_amdgcn_mfma_f32_16x16x32_bf16(kf[kt], qfrag, zf, 0, 0, 0);
        float pm = St[0][0];
#pragma unroll
        for (int kt = 0; kt < 4; kt++)
#pragma unroll
            for (int r = 0; r < 4; r++) pm = fmaxf(pm, St[kt][r]);
        pm = fmaxf(pm, __shfl_xor(pm, 16));
        pm = fmaxf(pm, __shfl_xor(pm, 32));
        float mn = fmaxf(m, pm);
        float rs = EXP2F(m - mn);
        float ps = 0.f;
#pragma unroll
        for (int kt = 0; kt < 4; kt++)
#pragma unroll
            for (int r = 0; r < 4; r++) {
                float p = EXP2F(St[kt][r] - mn);
                ps += p;
                Pt[w][kt * 16 + g * 4 + r][q16] = f2bf(p);
            }
        ps += __shfl_xor(ps, 16);
        ps += __shfl_xor(ps, 32);
        lsum = lsum * rs + ps;
        m = mn;
        O0 *= rs; O1 *= rs;
#pragma unroll
        for (int c = 0; c < 2; c++) {
            bf16x8 pb;
#pragma unroll
            for (int i = 0; i < 8; i++) pb[i] = Pt[w][c * 32 + g * 8 + i][q16];
            O0 = __builtin_amdgcn_mfma_f32_16x16x32_bf16(vf[c * 2 + 0], pb, O0, 0, 0, 0);
            O1 = __builtin_amdgcn_mfma_f32_16x16x32_bf16(vf[c * 2 + 1], pb, O1, 0, 0, 0);
        }
    };

    bf16x8 kA[4], kB[4], vA[4], vB[4];
    ldKV(kA, vA, 0);
    for (int t = 0; t < 32; t += 2) {
        if (t + 1 < 32) ldKV(kB, vB, t + 1);
        step(kA, vA);
        if (t + 2 < 32) ldKV(kA, vA, t + 2);
        step(kB, vB);
    }

    float inv = 1.f / lsum;
    float* op = o_out + ((size_t)(b * 2048 + qrow)) * 128 + 32 * h;
#pragma unroll
    for (int r = 0; r < 4; r++) {
        op[g * 4 + r]      = O0[r] * inv;
        op[16 + g * 4 + r] = O1[r] * inv;
    }
}

// ---------------- head ----------------
__global__ __launch_bounds__(128) void head_kernel(
    const float* __restrict__ x, const float* __restrict__ w,
    const float* __restrict__ bsp, const float* __restrict__ hw,
    const float* __restrict__ hb, float* __restrict__ out)
{
    int bb = blockIdx.x;
    int d = threadIdx.x;
    int wid = d >> 6, lane = d & 63;
    float v = x[(size_t)bb * 2048 * 128 + d];
    float s = v, sq = v * v;
#pragma unroll
    for (int o = 32; o > 0; o >>= 1) { s += __shfl_xor(s, o); sq += __shfl_xor(sq, o); }
    __shared__ float red[4];
    if (lane == 0) { red[wid] = s; red[2 + wid] = sq; }
    __syncthreads();
    s = red[0] + red[1]; sq = red[2] + red[3];
    float mu = s * (1.f / 128.f);
    float var = sq * (1.f / 128.f) - mu * mu;
    float xn = (v - mu) * rsqrtf(var + 1e-5f) * w[d] + bsp[d];
    float pr = xn * hw[d];
#pragma unroll
    for (int o = 32; o > 0; o >>= 1) pr += __shfl_xor(pr, o);
    __syncthreads();
    if (lane == 0) red[wid] = pr;
    __syncthreads();
    if (d == 0) out[bb] = red[0] + red[1] + hb[0];
}

// ---------------- workspace layout (floats) ----------------
constexpr size_t OFF_X  = 0;
constexpr size_t OFF_XN = (size_t)1 << 20;
constexpr size_t OFF_XZ = (size_t)2 << 20;
constexpr size_t OFF_XC = (size_t)6 << 20;
constexpr size_t OFF_DT = (size_t)8 << 20;
constexpr size_t OFF_Y  = (size_t)10 << 20;
constexpr size_t OFF_BM = (size_t)12 << 20;
constexpr size_t OFF_CM = OFF_BM + 131072;
constexpr size_t OFF_SD = OFF_CM + 131072;
constexpr size_t OFF_F  = OFF_SD + 65536;            // mamba F / attn kbf / embed enc
constexpr size_t OFF_HS = OFF_F + ((size_t)1 << 20); // mamba Hs / attn vbf
constexpr size_t WS_FLOATS = OFF_HS + ((size_t)1 << 20);

extern "C" void kernel_launch(void* const* d_in, const int* in_sizes, int n_in,
                              void* d_out, int out_size, void* d_ws, size_t ws_size,
                              hipStream_t stream)
{
    const int*   ids   = (const int*)d_in[0];
    const int*   tts   = (const int*)d_in[1];
    const float* tstmp = (const float*)d_in[2];
    const float* emb   = (const float*)d_in[3];
    const float* temb  = (const float*)d_in[4];
    const float* tef   = (const float*)d_in[5];
    const float* tep   = (const float*)d_in[6];
    const float* tew   = (const float*)d_in[7];
    const float* tebi  = (const float*)d_in[8];
    const float* mnw   = (const float*)d_in[9];
    const float* mnb   = (const float*)d_in[10];
    const float* minw  = (const float*)d_in[11];
    const float* mcwp  = (const float*)d_in[12];
    const float* mcb   = (const float*)d_in[13];
    const float* mdtw  = (const float*)d_in[14];
    const float* mdtb  = (const float*)d_in[15];
    const float* mbw   = (const float*)d_in[16];
    const float* mcw2  = (const float*)d_in[17];
    const float* mD    = (const float*)d_in[18];
    const float* mAl   = (const float*)d_in[19];
    const float* mow   = (const float*)d_in[20];
    const float* al1w  = (const float*)d_in[21];
    const float* al1b  = (const float*)d_in[22];
    const float* aqkvw = (const float*)d_in[23];
    const float* aqkvb = (const float*)d_in[24];
    const float* aow   = (const float*)d_in[25];
    const float* aob   = (const float*)d_in[26];
    const float* al2w  = (const float*)d_in[27];
    const float* al2b  = (const float*)d_in[28];
    const float* af1w  = (const float*)d_in[29];
    const float* af1b  = (const float*)d_in[30];
    const float* af2w  = (const float*)d_in[31];
    const float* af2b  = (const float*)d_in[32];
    const float* hlnw  = (const float*)d_in[33];
    const float* hlnb  = (const float*)d_in[34];
    const float* hw    = (const float*)d_in[35];
    const float* hb    = (const float*)d_in[36];
    float* out = (float*)d_out;
    float* wsf = (float*)d_ws;
    if (ws_size < WS_FLOATS * sizeof(float)) return;

    float* x   = wsf + OFF_X;
    float* xn  = wsf + OFF_XN;
    float* xz  = wsf + OFF_XZ;
    float* xc  = wsf + OFF_XC;
    float* dtb = wsf + OFF_DT;
    float* yb  = wsf + OFF_Y;
    float* bm  = wsf + OFF_BM;
    float* cm  = wsf + OFF_CM;
    float* sdb = wsf + OFF_SD;
    float* Fb  = wsf + OFF_F;
    float* Hsb = wsf + OFF_HS;
    float* qkv = xc;
    float* ff  = xz;
    float* aout = yb;
    float* encb = Fb;
    short* kbf = (short*)(wsf + OFF_F);
    short* vbf = (short*)(wsf + OFF_HS);

    gather_enc_kernel<<<TOK / 2, 256, 0, stream>>>(ids, tts, tstmp, emb, temb, tef, tep, x, encb);
    gemm_f16_kernel<0, true, true><<<dim3(128, 2), 256, 0, stream>>>(
        encb, tew, tebi, x, TOK, 128, 128, 128, 128);

    int mi = 0, ai = 0;
    for (int i = 0; i < 8; i++) {
        if ((i + 1) % 4 == 0) {
            // -------- attention layer --------
            ln_kernel<<<TOK / 4, 256, 0, stream>>>(x, al1w + ai * 128, al1b + ai * 128, xn);
            gemm_f16_kernel<0, true, false><<<dim3(128, 6), 256, 0, stream>>>(
                xn, aqkvw + (size_t)ai * 384 * 128, aqkvb + ai * 384, qkv, TOK, 384, 128, 128, 384);
            qkv_prep_kernel<<<dim3(32, Hh, Bb), 256, 0, stream>>>(qkv, kbf, vbf);
            attn_mfma_kernel<<<dim3(32, Hh, Bb), 256, 0, stream>>>(qkv, kbf, vbf, aout);
            gemm_f16_kernel<0, true, true><<<dim3(128, 2), 256, 0, stream>>>(
                aout, aow + (size_t)ai * 128 * 128, aob + ai * 128, x, TOK, 128, 128, 128, 128);
            ln_kernel<<<TOK / 4, 256, 0, stream>>>(x, al2w + ai * 128, al2b + ai * 128, xn);
            gemm_f16_kernel<2, true, false><<<dim3(128, 8), 256, 0, stream>>>(
                xn, af1w + (size_t)ai * 512 * 128, af1b + ai * 512, ff, TOK, 512, 128, 128, 512);
            gemm_f16_kernel<0, true, true><<<dim3(128, 2), 256, 0, stream>>>(
                ff, af2w + (size_t)ai * 128 * 512, af2b + ai * 128, x, TOK, 128, 512, 512, 128);
            ai++;
        } else {
            // -------- mamba layer --------
            const float* Al = mAl + (size_t)mi * DIi * 16;
            ln_kernel<<<TOK / 4, 256, 0, stream>>>(x, mnw + mi * 128, mnb + mi * 128, xn);
            gemm_f16_kernel<0, false, false><<<dim3(128, 8), 256, 0, stream>>>(
                xn, minw + (size_t)mi * 512 * 128, nullptr, xz, TOK, 512, 128, 128, 512);
            conv_kernel<<<8192, 256, 0, stream>>>(xz, mcwp + (size_t)mi * DIi * 4, mcb + mi * DIi, xc);
            gemm_f16_kernel<1, true, false><<<dim3(128, 4), 256, 0, stream>>>(
                xc, mdtw + (size_t)mi * 256 * 256, mdtb + mi * 256, dtb, TOK, 256, 256, 256, 256);
            bc_kernel<<<512, 256, 0, stream>>>(xc, mbw + (size_t)mi * 16 * 256, mcw2 + (size_t)mi * 16 * 256, bm, cm);
            scan1_kernel<<<Bb * NC, 256, 0, stream>>>(dtb, xc, bm, Al, Fb, sdb);
            scan2_kernel<<<64, 256, 0, stream>>>(Fb, sdb, Al, Hsb);
            scan3_kernel<<<Bb * NC, 256, 0, stream>>>(dtb, xc, bm, cm, xz, Al, mD + mi * 256, Hsb, yb);
            gemm_f16_kernel<0, false, true><<<dim3(128, 2), 256, 0, stream>>>(
                yb, mow + (size_t)mi * 128 * 256, nullptr, x, TOK, 128, 256, 256, 128);
            mi++;
        }
    }
    head_kernel<<<Bb, 128, 0, stream>>>(x, hlnw, hlnb, hw, hb, out);
}